// Round 11
// baseline (398.070 us; speedup 1.0000x reference)
//
#include <hip/hip_runtime.h>

// SPN forward, round 11 (= round 9/10 kernel; 2x infra flake, never ran).
// DRAM-page-friendly producer reshape: 8 producer waves (32 rows each) load
// 32-col "supers" with instructions shaped 8 rows x 128B-contiguous, 16
// loads back-to-back per burst -> 128B per page activation + 2x MLP vs
// rounds 1-8 (which plateaued at ~4.3 B/cy/CU regardless of schedule).
// Supers double-buffered in registers (even->PA, odd->PB, static indices),
// normalized once, dribbled into the proven 16-col 2-slot LDS ring.
// Consumer identical to round 8. Uniform barrier count (17/17), lgkm-only.

#define HD 256
#define WD 256
#define STG 260                 // padded column stride (floats)
#define ARR_F (16 * STG)        // one array, one 16-col ring slot
#define STAGE_F (4 * ARR_F)     // d, g1, g2, g3
#define TILE_OFF (2 * STAGE_F)  // out tile after the 2-deep ring

#define F4E(v, e) ((e) == 0 ? (v).x : (e) == 1 ? (v).y : (e) == 2 ? (v).z : (v).w)

#define FENCE_BAR()                                      \
  do {                                                   \
    asm volatile("s_waitcnt lgkmcnt(0)" ::: "memory");   \
    __builtin_amdgcn_s_barrier();                        \
    asm volatile("" ::: "memory");                       \
  } while (0)

__global__ __launch_bounds__(576, 1) void spn_fwd(
    const float* __restrict__ x, const float* __restrict__ G1,
    const float* __restrict__ G2, const float* __restrict__ G3,
    float* __restrict__ out)
{
  __shared__ float lds_f[2 * STAGE_F + 16 * STG];   // 149,760 B -> 1 block/CU

  const int tid = threadIdx.x;
  const int wv  = tid >> 6;          // 0..7 producers, 8 consumer
  const int l   = tid & 63;
  const size_t pbase = (size_t)blockIdx.x * (HD * WD);
  const float* gp[4] = {x + pbase, G1 + pbase, G2 + pbase, G3 + pbase};
  float* op = out + pbase;

  if (wv < 8) {
    // ============ PRODUCER (rows 32*wv .. 32*wv+31) ============
    const int r8 = l >> 3;           // row within 8-row group (0..7)
    const int p8 = l & 7;            // 16B piece within 128B super-row (0..7)
    float4 PA[4][4], PB[4][4];       // [array][rowgroup i]; one 32-col super

    // one burst = 16 back-to-back loads, each 8 rows x 128B contiguous
    auto burst = [&](float4 (&P)[4][4], int s) {
#pragma unroll
      for (int A = 0; A < 4; ++A)
#pragma unroll
        for (int i = 0; i < 4; ++i)
          P[A][i] = *(const float4*)(gp[A] +
              (size_t)(32 * wv + 8 * i + r8) * WD + 32 * s + 4 * p8);
    };

    // normalize + boundary masks for the whole super (done once per super)
    auto normSuper = [&](float4 (&P)[4][4], int s) {
#pragma unroll
      for (int i = 0; i < 4; ++i) {
        const int row = 32 * wv + 8 * i + r8;
        const float uOk = (row > 0) ? 1.f : 0.f;
        const float dOk = (row < HD - 1) ? 1.f : 0.f;
        float nx[4], na[4], nb[4], nc[4];
#pragma unroll
        for (int e = 0; e < 4; ++e) {
          float a = F4E(P[1][i], e), b = F4E(P[2][i], e), c = F4E(P[3][i], e);
          float xx = F4E(P[0][i], e);
          float ssum = fabsf(a) + fabsf(b) + fabsf(c);
          float inv = (ssum >= 1.f) ? __builtin_amdgcn_rcpf(ssum) : 1.f;
          float cOk = (32 * s + 4 * p8 + e > 0) ? 1.f : 0.f;  // global col 0
          float ga = a * inv * cOk * uOk;
          float gb = b * inv * cOk;
          float gc = c * inv * cOk * dOk;
          nx[e] = (1.f - ga - gb - gc) * xx;
          na[e] = ga; nb[e] = gb; nc[e] = gc;
        }
        P[0][i] = make_float4(nx[0], nx[1], nx[2], nx[3]);
        P[1][i] = make_float4(na[0], na[1], na[2], na[3]);
        P[2][i] = make_float4(nb[0], nb[1], nb[2], nb[3]);
        P[3][i] = make_float4(nc[0], nc[1], nc[2], nc[3]);
      }
    };

    // write one 16-col half (h) of the held super into a ring slot
    auto writeSlice = [&](float4 (&P)[4][4], int h, float* slot) {
      if (((l >> 2) & 1) == h) {               // lanes holding this half
        const int c0 = (4 * p8) & 15;          // slot-local col base {0,4,8,12}
#pragma unroll
        for (int A = 0; A < 4; ++A)
#pragma unroll
          for (int i = 0; i < 4; ++i) {
            const int row = 32 * wv + 8 * i + r8;
#pragma unroll
            for (int e = 0; e < 4; ++e)
              slot[A * ARR_F + (c0 + e) * STG + row] = F4E(P[A][i], e);
          }
      }
    };

    // prologue: super0 -> PA -> stage0 (slot0); super1 -> PB in flight
    burst(PA, 0);
    normSuper(PA, 0);
    writeSlice(PA, 0, lds_f + 0 * STAGE_F);
    burst(PB, 1);
    FENCE_BAR();

    // interval t writes stage t+1 into slot (t+1)&1. Super of stage t+1 =
    // (t+1)>>1; even supers live in PA, odd in PB. Bursts go 2 intervals
    // before first use; issued BEFORE the norm so the norm's vmcnt wait
    // leaves the new burst in flight (FIFO-precise).
#pragma unroll 1
    for (int g = 0; g < 4; ++g) {
      // t=4g: stage 4g+1 = slice1 of super 2g (PA)
      writeSlice(PA, 1, lds_f + 1 * STAGE_F);
      FENCE_BAR();
      // t=4g+1: burst super 2g+2 -> PA; stage 4g+2 = slice0 of super 2g+1 (PB)
      if (g < 3) burst(PA, 2 * g + 2);
      normSuper(PB, 2 * g + 1);
      writeSlice(PB, 0, lds_f + 0 * STAGE_F);
      FENCE_BAR();
      // t=4g+2: stage 4g+3 = slice1 of super 2g+1 (PB)
      writeSlice(PB, 1, lds_f + 1 * STAGE_F);
      FENCE_BAR();
      // t=4g+3: burst super 2g+3 -> PB; stage 4g+4 = slice0 of super 2g+2 (PA)
      if (g < 3) {
        burst(PB, 2 * g + 3);
        normSuper(PA, 2 * g + 2);
        writeSlice(PA, 0, lds_f + 0 * STAGE_F);
      }
      FENCE_BAR();
    }
  } else {
    // ===================== CONSUMER (serial scan) =====================
    float h[4] = {0.f, 0.f, 0.f, 0.f};
    const int cb = 4 * (l & 3);
    const int rr = l >> 2;
    float* tile = lds_f + TILE_OFF;

    FENCE_BAR();   // matches producer prologue barrier

#pragma unroll 1
    for (int t = 0; t < 16; ++t) {
      const float* src = lds_f + (t & 1) * STAGE_F;
      float4 rd[2][4];                 // [phase][array], one column each

      // preload column 0
#pragma unroll
      for (int A = 0; A < 4; ++A)
        rd[0][A] = *(const float4*)(src + A * ARR_F + 0 * STG + 4 * l);

#pragma unroll
      for (int c = 0; c < 16; ++c) {
        const int cur = c & 1, nxt = cur ^ 1;
        if (c < 15) {
#pragma unroll
          for (int A = 0; A < 4; ++A)
            rd[nxt][A] = *(const float4*)(src + A * ARR_F + (c + 1) * STG + 4 * l);
        }
        const float shU = __shfl_up(h[3], 1);    // h[4l-1]
        const float shD = __shfl_down(h[0], 1);  // h[4l+4]
        float hn[4];
#pragma unroll
        for (int r = 0; r < 4; ++r) {
          float up = (r == 0) ? shU : h[r - 1];
          float dn = (r == 3) ? shD : h[r + 1];
          hn[r] = fmaf(F4E(rd[cur][1], r), up,
                  fmaf(F4E(rd[cur][2], r), h[r],
                  fmaf(F4E(rd[cur][3], r), dn, F4E(rd[cur][0], r))));
        }
#pragma unroll
        for (int r = 0; r < 4; ++r) h[r] = hn[r];
        *(float4*)(tile + c * STG + 4 * l) =
            make_float4(hn[0], hn[1], hn[2], hn[3]);
      }

      // gather rows -> full-64B-line coalesced stores (16 cols per stage)
#pragma unroll
      for (int kk = 0; kk < 16; ++kk) {
        const int row = 16 * kk + rr;
        float4 o;
        o.x = tile[(cb + 0) * STG + row];
        o.y = tile[(cb + 1) * STG + row];
        o.z = tile[(cb + 2) * STG + row];
        o.w = tile[(cb + 3) * STG + row];
        *(float4*)(op + (size_t)row * WD + 16 * t + cb) = o;
      }
      FENCE_BAR();
    }
  }
}

extern "C" void kernel_launch(void* const* d_in, const int* in_sizes, int n_in,
                              void* d_out, int out_size, void* d_ws, size_t ws_size,
                              hipStream_t stream) {
  const float* x  = (const float*)d_in[0];
  const float* g1 = (const float*)d_in[1];
  const float* g2 = (const float*)d_in[2];
  const float* g3 = (const float*)d_in[3];
  float* outp = (float*)d_out;
  const int planes = out_size / (HD * WD);   // B*C = 256
  spn_fwd<<<planes, 576, 0, stream>>>(x, g1, g2, g3, outp);
}

// Round 12
// 290.804 us; speedup vs baseline: 1.3689x; 1.3689x over previous
//
#include <hip/hip_runtime.h>

// SPN forward, round 12: round-8 skeleton (4 producer waves + 1 consumer,
// 16-col 2-slot LDS ring, lgkm-only barriers) with DRAM-page-friendly
// producer loads, kept inside the 5-wave VGPR envelope (cap 256; round 11's
// 9-wave variant spilled at cap 170 -> 398us of scratch traffic).
// Producer: one 32-col super per 2 intervals, 32 back-to-back loads shaped
// 8 rows x 128B-contiguous (128B per DRAM page activation, 2x round 8).
// Single 128-VGPR payload P[4][8]; freed at slice1-write; burst(s+1) goes
// one interval before its norm. Consumer verbatim round 8.

#define HD 256
#define WD 256
#define STG 260                 // padded column stride (floats)
#define ARR_F (16 * STG)        // one array, one 16-col ring slot
#define STAGE_F (4 * ARR_F)     // d, g1, g2, g3
#define TILE_OFF (2 * STAGE_F)  // out tile after the 2-deep ring

#define F4E(v, e) ((e) == 0 ? (v).x : (e) == 1 ? (v).y : (e) == 2 ? (v).z : (v).w)

#define FENCE_BAR()                                      \
  do {                                                   \
    asm volatile("s_waitcnt lgkmcnt(0)" ::: "memory");   \
    __builtin_amdgcn_s_barrier();                        \
    asm volatile("" ::: "memory");                       \
  } while (0)

__global__ __launch_bounds__(320, 1) void spn_fwd(
    const float* __restrict__ x, const float* __restrict__ G1,
    const float* __restrict__ G2, const float* __restrict__ G3,
    float* __restrict__ out)
{
  __shared__ float lds_f[2 * STAGE_F + 16 * STG];   // 149,760 B -> 1 block/CU

  const int tid = threadIdx.x;
  const int wid = tid >> 6;          // 0..3 producers, 4 consumer
  const int l   = tid & 63;
  const size_t pbase = (size_t)blockIdx.x * (HD * WD);
  const float* gp[4] = {x + pbase, G1 + pbase, G2 + pbase, G3 + pbase};
  float* op = out + pbase;

  if (wid < 4) {
    // ============ PRODUCER (rows 64*wid .. 64*wid+63) ============
    const int r8 = l >> 3;           // row within 8-row group (0..7)
    const int p8 = l & 7;            // 16B piece within 128B span (0..7)
    float4 P[4][8];                  // [array][rowgroup i]: one 32-col super
                                     // = 128 VGPRs payload (cap 256 at 5 waves)

    // one burst = 32 back-to-back loads, each 8 rows x 128B contiguous
    auto burst = [&](int s) {
#pragma unroll
      for (int A = 0; A < 4; ++A)
#pragma unroll
        for (int i = 0; i < 8; ++i)
          P[A][i] = *(const float4*)(gp[A] +
              (size_t)(64 * wid + 8 * i + r8) * WD + 32 * s + 4 * p8);
    };

    // normalize + boundary masks in place; x-slot := (1-ga-gb-gc)*x
    auto normSuper = [&](int s) {
#pragma unroll
      for (int i = 0; i < 8; ++i) {
        const int row = 64 * wid + 8 * i + r8;
        const float uOk = (row > 0) ? 1.f : 0.f;
        const float dOk = (row < HD - 1) ? 1.f : 0.f;
        float nx[4], na[4], nb[4], nc[4];
#pragma unroll
        for (int e = 0; e < 4; ++e) {
          float a = F4E(P[1][i], e), b = F4E(P[2][i], e), c = F4E(P[3][i], e);
          float xx = F4E(P[0][i], e);
          float ssum = fabsf(a) + fabsf(b) + fabsf(c);
          float inv = (ssum >= 1.f) ? __builtin_amdgcn_rcpf(ssum) : 1.f;
          float cOk = (32 * s + 4 * p8 + e > 0) ? 1.f : 0.f;  // global col 0
          float ga = a * inv * cOk * uOk;
          float gb = b * inv * cOk;
          float gc = c * inv * cOk * dOk;
          nx[e] = (1.f - ga - gb - gc) * xx;
          na[e] = ga; nb[e] = gb; nc[e] = gc;
        }
        P[0][i] = make_float4(nx[0], nx[1], nx[2], nx[3]);
        P[1][i] = make_float4(na[0], na[1], na[2], na[3]);
        P[2][i] = make_float4(nb[0], nb[1], nb[2], nb[3]);
        P[3][i] = make_float4(nc[0], nc[1], nc[2], nc[3]);
      }
    };

    // write one 16-col half (h) of the super into a ring slot.
    // lanes with p8>>2==h hold this half; slot-local col base = 4*(p8&3).
    auto writeSlice = [&](int h, float* slot) {
      if ((p8 >> 2) == h) {
        const int c0 = 4 * (p8 & 3);
#pragma unroll
        for (int A = 0; A < 4; ++A)
#pragma unroll
          for (int i = 0; i < 8; ++i) {
            const int row = 64 * wid + 8 * i + r8;
#pragma unroll
            for (int e = 0; e < 4; ++e)
              slot[A * ARR_F + (c0 + e) * STG + row] = F4E(P[A][i], e);
          }
      }
    };

    // prologue: super0 loaded, normed, slice0 -> slot0 (stage 0)
    burst(0);
    normSuper(0);
    writeSlice(0, lds_f + 0 * STAGE_F);
    FENCE_BAR();

    // super k covers stages {2k, 2k+1}. Interval 2k: slice1(k) -> slot1
    // (stage 2k+1), then burst(k+1) into the freed payload. Interval 2k+1:
    // norm(k+1) (vmcnt wait on the burst) + slice0(k+1) -> slot0.
#pragma unroll 1
    for (int k = 0; k < 8; ++k) {
      writeSlice(1, lds_f + 1 * STAGE_F);    // stage 2k+1
      if (k < 7) burst(k + 1);               // payload free; loads in flight
      FENCE_BAR();
      if (k < 7) {
        normSuper(k + 1);
        writeSlice(0, lds_f + 0 * STAGE_F);  // stage 2k+2
      }
      FENCE_BAR();
    }
  } else {
    // ===================== CONSUMER (serial scan) =====================
    float h[4] = {0.f, 0.f, 0.f, 0.f};
    const int cb = 4 * (l & 3);
    const int rr = l >> 2;
    float* tile = lds_f + TILE_OFF;

    FENCE_BAR();   // matches producer prologue barrier

#pragma unroll 1
    for (int t = 0; t < 16; ++t) {
      const float* src = lds_f + (t & 1) * STAGE_F;
      float4 rd[2][4];                 // [phase][array], one column each

      // preload column 0
#pragma unroll
      for (int A = 0; A < 4; ++A)
        rd[0][A] = *(const float4*)(src + A * ARR_F + 0 * STG + 4 * l);

#pragma unroll
      for (int c = 0; c < 16; ++c) {
        const int cur = c & 1, nxt = cur ^ 1;
        if (c < 15) {
#pragma unroll
          for (int A = 0; A < 4; ++A)
            rd[nxt][A] = *(const float4*)(src + A * ARR_F + (c + 1) * STG + 4 * l);
        }
        const float shU = __shfl_up(h[3], 1);    // h[4l-1]
        const float shD = __shfl_down(h[0], 1);  // h[4l+4]
        float hn[4];
#pragma unroll
        for (int r = 0; r < 4; ++r) {
          float up = (r == 0) ? shU : h[r - 1];
          float dn = (r == 3) ? shD : h[r + 1];
          hn[r] = fmaf(F4E(rd[cur][1], r), up,
                  fmaf(F4E(rd[cur][2], r), h[r],
                  fmaf(F4E(rd[cur][3], r), dn, F4E(rd[cur][0], r))));
        }
#pragma unroll
        for (int r = 0; r < 4; ++r) h[r] = hn[r];
        *(float4*)(tile + c * STG + 4 * l) =
            make_float4(hn[0], hn[1], hn[2], hn[3]);
      }

      // gather rows -> full-64B-line coalesced stores (16 cols per stage)
#pragma unroll
      for (int kk = 0; kk < 16; ++kk) {
        const int row = 16 * kk + rr;
        float4 o;
        o.x = tile[(cb + 0) * STG + row];
        o.y = tile[(cb + 1) * STG + row];
        o.z = tile[(cb + 2) * STG + row];
        o.w = tile[(cb + 3) * STG + row];
        *(float4*)(op + (size_t)row * WD + 16 * t + cb) = o;
      }
      FENCE_BAR();
    }
  }
}

extern "C" void kernel_launch(void* const* d_in, const int* in_sizes, int n_in,
                              void* d_out, int out_size, void* d_ws, size_t ws_size,
                              hipStream_t stream) {
  const float* x  = (const float*)d_in[0];
  const float* g1 = (const float*)d_in[1];
  const float* g2 = (const float*)d_in[2];
  const float* g3 = (const float*)d_in[3];
  float* outp = (float*)d_out;
  const int planes = out_size / (HD * WD);   // B*C = 256
  spn_fwd<<<planes, 320, 0, stream>>>(x, g1, g2, g3, outp);
}

// Round 13
// 118.304 us; speedup vs baseline: 3.3648x; 2.4581x over previous
//
#include <hip/hip_runtime.h>

// SPN forward, round 13: page-grain loads INSIDE the register envelope.
// 8 producer waves (32 rows each) + 1 consumer wave = 576 threads.
// Producer burst = 16 back-to-back insts, each 8 rows x 128B contiguous
// (32-col super); payload 64 VGPR/lane; super k dies (slice1 ds_write)
// BEFORE burst k+1 issues -> max live ~90 regs, no spill (rounds 11/12
// failed here). Norm gap = one full interval. 16-col 2-slot LDS ring,
// lgkm-only fences, 17/17 barriers. Consumer verbatim round 8.

#define HD 256
#define WD 256
#define STG 260                 // padded column stride (floats)
#define ARR_F (16 * STG)        // one array, one 16-col ring slot
#define STAGE_F (4 * ARR_F)     // d, g1, g2, g3
#define TILE_OFF (2 * STAGE_F)  // out tile after the 2-deep ring

#define F4E(v, e) ((e) == 0 ? (v).x : (e) == 1 ? (v).y : (e) == 2 ? (v).z : (v).w)

#define FENCE_BAR()                                      \
  do {                                                   \
    asm volatile("s_waitcnt lgkmcnt(0)" ::: "memory");   \
    __builtin_amdgcn_s_barrier();                        \
    asm volatile("" ::: "memory");                       \
  } while (0)

__global__ __launch_bounds__(576, 2) void spn_fwd(
    const float* __restrict__ x, const float* __restrict__ G1,
    const float* __restrict__ G2, const float* __restrict__ G3,
    float* __restrict__ out)
{
  __shared__ float lds_f[2 * STAGE_F + 16 * STG];   // 149,760 B -> 1 block/CU

  const int tid = threadIdx.x;
  const int wv  = tid >> 6;          // 0..7 producers, 8 consumer
  const int l   = tid & 63;
  const size_t pbase = (size_t)blockIdx.x * (HD * WD);
  const float* gp[4] = {x + pbase, G1 + pbase, G2 + pbase, G3 + pbase};
  float* op = out + pbase;

  if (wv < 8) {
    // ============ PRODUCER (rows 32*wv .. 32*wv+31) ============
    const int r8 = l >> 3;           // row within 8-row group (0..7)
    const int p8 = l & 7;            // 16B piece within 128B span (0..7)
    float4 P[4][4];                  // [array][rowgroup i]: 64 VGPR payload

    // burst: 16 back-to-back loads, each 8 rows x 128B contiguous
    auto burst = [&](int s) {
#pragma unroll
      for (int A = 0; A < 4; ++A)
#pragma unroll
        for (int i = 0; i < 4; ++i)
          P[A][i] = *(const float4*)(gp[A] +
              (size_t)(32 * wv + 8 * i + r8) * WD + 32 * s + 4 * p8);
    };

    // normalize + boundary masks in place; x-slot := (1-ga-gb-gc)*x
    auto normSuper = [&](int s) {
#pragma unroll
      for (int i = 0; i < 4; ++i) {
        const int row = 32 * wv + 8 * i + r8;
        const float uOk = (row > 0) ? 1.f : 0.f;
        const float dOk = (row < HD - 1) ? 1.f : 0.f;
        float nx[4], na[4], nb[4], nc[4];
#pragma unroll
        for (int e = 0; e < 4; ++e) {
          float a = F4E(P[1][i], e), b = F4E(P[2][i], e), c = F4E(P[3][i], e);
          float xx = F4E(P[0][i], e);
          float ssum = fabsf(a) + fabsf(b) + fabsf(c);
          float inv = (ssum >= 1.f) ? __builtin_amdgcn_rcpf(ssum) : 1.f;
          float cOk = (32 * s + 4 * p8 + e > 0) ? 1.f : 0.f;  // global col 0
          float ga = a * inv * cOk * uOk;
          float gb = b * inv * cOk;
          float gc = c * inv * cOk * dOk;
          nx[e] = (1.f - ga - gb - gc) * xx;
          na[e] = ga; nb[e] = gb; nc[e] = gc;
        }
        P[0][i] = make_float4(nx[0], nx[1], nx[2], nx[3]);
        P[1][i] = make_float4(na[0], na[1], na[2], na[3]);
        P[2][i] = make_float4(nb[0], nb[1], nb[2], nb[3]);
        P[3][i] = make_float4(nc[0], nc[1], nc[2], nc[3]);
      }
    };

    // write one 16-col half (h) of the super into a ring slot.
    // lanes with p8>>2==h hold this half; slot-local col base = 4*(p8&3).
    // banks: 16 distinct across 32 active lanes -> 2-way, free.
    auto writeSlice = [&](int h, float* slot) {
      if ((p8 >> 2) == h) {
        const int c0 = 4 * (p8 & 3);
#pragma unroll
        for (int A = 0; A < 4; ++A)
#pragma unroll
          for (int i = 0; i < 4; ++i) {
            const int row = 32 * wv + 8 * i + r8;
#pragma unroll
            for (int e = 0; e < 4; ++e)
              slot[A * ARR_F + (c0 + e) * STG + row] = F4E(P[A][i], e);
          }
      }
    };

    // prologue: super 0 -> stage 0 (slot 0)
    burst(0);
    normSuper(0);
    writeSlice(0, lds_f + 0 * STAGE_F);
    FENCE_BAR();

    // super k covers stages {2k, 2k+1}.
    // interval 2k:   slice1(k) -> slot1 (payload k dies), burst(k+1)
    // interval 2k+1: norm(k+1) (one-interval-old loads), slice0 -> slot0
#pragma unroll 1
    for (int k = 0; k < 8; ++k) {
      writeSlice(1, lds_f + 1 * STAGE_F);    // stage 2k+1
      if (k < 7) burst(k + 1);               // payload free; 16 insts in flight
      FENCE_BAR();
      if (k < 7) {
        normSuper(k + 1);
        writeSlice(0, lds_f + 0 * STAGE_F);  // stage 2k+2
      }
      FENCE_BAR();
    }
  } else {
    // ===================== CONSUMER (serial scan) =====================
    float h[4] = {0.f, 0.f, 0.f, 0.f};
    const int cb = 4 * (l & 3);
    const int rr = l >> 2;
    float* tile = lds_f + TILE_OFF;

    FENCE_BAR();   // matches producer prologue barrier

#pragma unroll 1
    for (int t = 0; t < 16; ++t) {
      const float* src = lds_f + (t & 1) * STAGE_F;
      float4 rd[2][4];                 // [phase][array], one column each

      // preload column 0
#pragma unroll
      for (int A = 0; A < 4; ++A)
        rd[0][A] = *(const float4*)(src + A * ARR_F + 0 * STG + 4 * l);

#pragma unroll
      for (int c = 0; c < 16; ++c) {
        const int cur = c & 1, nxt = cur ^ 1;
        if (c < 15) {
#pragma unroll
          for (int A = 0; A < 4; ++A)
            rd[nxt][A] = *(const float4*)(src + A * ARR_F + (c + 1) * STG + 4 * l);
        }
        const float shU = __shfl_up(h[3], 1);    // h[4l-1]
        const float shD = __shfl_down(h[0], 1);  // h[4l+4]
        float hn[4];
#pragma unroll
        for (int r = 0; r < 4; ++r) {
          float up = (r == 0) ? shU : h[r - 1];
          float dn = (r == 3) ? shD : h[r + 1];
          hn[r] = fmaf(F4E(rd[cur][1], r), up,
                  fmaf(F4E(rd[cur][2], r), h[r],
                  fmaf(F4E(rd[cur][3], r), dn, F4E(rd[cur][0], r))));
        }
#pragma unroll
        for (int r = 0; r < 4; ++r) h[r] = hn[r];
        *(float4*)(tile + c * STG + 4 * l) =
            make_float4(hn[0], hn[1], hn[2], hn[3]);
      }

      // gather rows -> full-64B-line coalesced stores (16 cols per stage)
#pragma unroll
      for (int kk = 0; kk < 16; ++kk) {
        const int row = 16 * kk + rr;
        float4 o;
        o.x = tile[(cb + 0) * STG + row];
        o.y = tile[(cb + 1) * STG + row];
        o.z = tile[(cb + 2) * STG + row];
        o.w = tile[(cb + 3) * STG + row];
        *(float4*)(op + (size_t)row * WD + 16 * t + cb) = o;
      }
      FENCE_BAR();
    }
  }
}

extern "C" void kernel_launch(void* const* d_in, const int* in_sizes, int n_in,
                              void* d_out, int out_size, void* d_ws, size_t ws_size,
                              hipStream_t stream) {
  const float* x  = (const float*)d_in[0];
  const float* g1 = (const float*)d_in[1];
  const float* g2 = (const float*)d_in[2];
  const float* g3 = (const float*)d_in[3];
  float* outp = (float*)d_out;
  const int planes = out_size / (HD * WD);   // B*C = 256
  spn_fwd<<<planes, 576, 0, stream>>>(x, g1, g2, g3, outp);
}